// Round 2
// baseline (2829.952 us; speedup 1.0000x reference)
//
#include <hip/hip_runtime.h>

typedef unsigned short u16;
typedef unsigned int u32;
typedef __attribute__((ext_vector_type(8))) short short8;
typedef __attribute__((ext_vector_type(8))) u16 u16x8;
typedef __attribute__((ext_vector_type(4))) u16 u16x4;
typedef __attribute__((ext_vector_type(4))) float f32x4;

#define DEVINL static __device__ __forceinline__

DEVINL float bf2f(u16 u) { return __uint_as_float(((u32)u) << 16); }
DEVINL u16 f2bf(float f) {  // RNE round to bf16
  u32 x = __float_as_uint(f);
  u32 r = (x + 0x7fffu + ((x >> 16) & 1u)) >> 16;
  return (u16)r;
}
DEVINL float fast_tanh(float x) {
  float cx = fminf(fmaxf(x, -15.f), 15.f);
  float e = __expf(2.f * cx);
  return (e - 1.f) / (e + 1.f);
}
DEVINL float sigm(float x) { return 1.f / (1.f + __expf(-x)); }

typedef __attribute__((address_space(1))) const void gvoid;
typedef __attribute__((address_space(3))) void svoid;
DEVINL void gld16(const void* g, void* l) {
  __builtin_amdgcn_global_load_lds((gvoid*)g, (svoid*)l, 16, 0, 0);
}

// Grid barrier (all blocks co-resident via cooperative launch).
// Sense via monotonically increasing generation counter. threadfence =
// agent-scope acq_rel -> emits L1 invalidate (G16: per-CU L1 non-coherent).
DEVINL void gridbar(u32* bar, u32 nblk) {
  __syncthreads();
  if (threadIdx.x == 0) {
    volatile u32* gen = bar + 1;
    u32 g = *gen;
    __threadfence();  // release this block's prior writes
    if (atomicAdd(bar, 1u) == nblk - 1) {
      atomicExch(bar, 0u);
      __threadfence();
      atomicAdd((u32*)(bar + 1), 1u);
    } else {
      while (*gen == g) __builtin_amdgcn_s_sleep(2);
    }
    __threadfence();  // acquire: invalidate L1 before consuming others' writes
  }
  __syncthreads();
}

// ---------------------------------------------------------------------------
// Phase 1: cast / gather / permute everything once (grid-stride, region table)
//  0 feat_bf   12845056  features f32 -> bf16
//  1 Waf_bf     1048576  W_attn_feat -> bf16
//  2 WahT8      262144   W_attn_h -> [k/8][512][8] bf16
//  3 Wcat       5242880  [2048 perm rows][2560]: k<2048 -> W_ih[:,512+k], else W_hh
//  4 Wemb       1048576  [2048 perm rows][512] = W_ih[:, :512]
//  5 bias_perm  2048     (b_ih + b_hh)[perm]
//  6 Wout_bf    5242880  [10240 pad][512], pad rows = 0
//  7 emb_bf     2097152  [m=t*128+b][512] = embed_w[captions[b][t]]
//  8 zeros_bf   512
//  9 bar        2        grid-barrier counters = 0
// perm row r <-> orig gate row o = (r&3)*512 + (r>>2)
// ---------------------------------------------------------------------------
__global__ __launch_bounds__(256) void cast_all(
    const float* __restrict__ features, const int* __restrict__ captions,
    const float* __restrict__ embed_w, const float* __restrict__ Waf,
    const float* __restrict__ Wah, const float* __restrict__ W_ih,
    const float* __restrict__ W_hh, const float* __restrict__ b_ih,
    const float* __restrict__ b_hh, const float* __restrict__ W_out,
    u16* __restrict__ feat_bf, u16* __restrict__ Waf_bf,
    u16* __restrict__ WahT8, u16* __restrict__ Wcat, u16* __restrict__ Wemb,
    float* __restrict__ bias_perm, u16* __restrict__ Wout_bf,
    u16* __restrict__ emb_bf, u16* __restrict__ zeros_bf,
    u32* __restrict__ bar) {
  long long i = (long long)blockIdx.x * 256 + threadIdx.x;
  const long long total = 27789826LL;
  const long long stride = (long long)gridDim.x * 256;
  for (; i < total; i += stride) {
    long long r = i;
    if (r < 12845056LL) { feat_bf[r] = f2bf(features[r]); continue; }
    r -= 12845056LL;
    if (r < 1048576LL) { Waf_bf[r] = f2bf(Waf[r]); continue; }
    r -= 1048576LL;
    if (r < 262144LL) {
      long long kb = r >> 12, rem = r & 4095;
      long long row = rem >> 3, e = rem & 7;
      WahT8[r] = f2bf(Wah[row * 512 + (kb * 8 + e)]);
      continue;
    }
    r -= 262144LL;
    if (r < 5242880LL) {
      long long pr = r / 2560, k = r % 2560;
      long long o = (pr & 3) * 512 + (pr >> 2);
      float v = (k < 2048) ? W_ih[o * 2560 + 512 + k] : W_hh[o * 512 + (k - 2048)];
      Wcat[r] = f2bf(v);
      continue;
    }
    r -= 5242880LL;
    if (r < 1048576LL) {
      long long pr = r >> 9, k = r & 511;
      long long o = (pr & 3) * 512 + (pr >> 2);
      Wemb[r] = f2bf(W_ih[o * 2560 + k]);
      continue;
    }
    r -= 1048576LL;
    if (r < 2048LL) {
      long long o = (r & 3) * 512 + (r >> 2);
      bias_perm[r] = b_ih[o] + b_hh[o];
      continue;
    }
    r -= 2048LL;
    if (r < 5242880LL) {
      long long row = r >> 9, k = r & 511;
      Wout_bf[r] = (row < 10000) ? f2bf(W_out[row * 512 + k]) : (u16)0;
      continue;
    }
    r -= 5242880LL;
    if (r < 2097152LL) {
      long long m = r >> 9, k = r & 511;
      long long tt = m >> 7, b = m & 127;
      int tok = captions[b * 32 + tt];
      tok = tok < 0 ? 0 : (tok > 9999 ? 9999 : tok);
      emb_bf[r] = f2bf(embed_w[(long long)tok * 512 + k]);
      continue;
    }
    r -= 2097152LL;
    if (r < 512LL) { zeros_bf[r] = 0; continue; }
    r -= 512LL;
    bar[r] = 0u;
  }
}

// ---------------------------------------------------------------------------
// 128x128 bf16 MFMA GEMM (2D grid): C[m][n] = sum_k A[m][k]*B[n][k] (+bias).
// XOR-swizzled LDS (off ^= (row&3)<<4) via pre-swizzled global src (rule 21).
// ---------------------------------------------------------------------------
__global__ __launch_bounds__(256) void gemm128(
    const u16* __restrict__ A, const u16* __restrict__ B,
    float* __restrict__ C, const float* __restrict__ bias,
    int K, int ldC, int Nvalid) {
  const int n0 = blockIdx.x * 128, m0 = blockIdx.y * 128;
  const int tid = threadIdx.x, w = tid >> 6, l = tid & 63;
  const int wm = w >> 1, wn = w & 1;
  __shared__ __align__(16) u16 As[2][128 * 32];
  __shared__ __align__(16) u16 Bs[2][128 * 32];
  const f32x4 z4 = {0.f, 0.f, 0.f, 0.f};
  f32x4 acc[4][4];
#pragma unroll
  for (int a_ = 0; a_ < 4; ++a_)
#pragma unroll
    for (int b_ = 0; b_ < 4; ++b_) acc[a_][b_] = z4;

  const int NT = K >> 5;
  const size_t rs = (size_t)K * 2;

  auto stage = [&](int buf, int kt) {
    const char* Ab = (const char*)A + (size_t)m0 * rs + (size_t)kt * 64;
    const char* Bb = (const char*)B + (size_t)n0 * rs + (size_t)kt * 64;
#pragma unroll
    for (int j = 0; j < 2; ++j) {
      int c = j * 256 + tid;
      int row = c >> 2, off = ((c & 3) * 16) ^ ((row & 3) << 4);
      char* la = (char*)&As[buf][0] + (size_t)(j * 256 + w * 64) * 16;
      char* lb = (char*)&Bs[buf][0] + (size_t)(j * 256 + w * 64) * 16;
      gld16(Ab + (size_t)row * rs + off, la);
      gld16(Bb + (size_t)row * rs + off, lb);
    }
  };

  stage(0, 0);
  int cur = 0;
  const int lg = l >> 4, lr = l & 15;
  for (int kt = 0; kt < NT; ++kt) {
    __syncthreads();
    if (kt + 1 < NT) stage(cur ^ 1, kt + 1);
    short8 a[4], bb[4];
#pragma unroll
    for (int mi = 0; mi < 4; ++mi) {
      int row = wm * 64 + mi * 16 + lr;
      a[mi] = *(const short8*)((const char*)&As[cur][0] + (size_t)row * 64 + ((lg * 16) ^ ((row & 3) << 4)));
    }
#pragma unroll
    for (int ni = 0; ni < 4; ++ni) {
      int row = wn * 64 + ni * 16 + lr;
      bb[ni] = *(const short8*)((const char*)&Bs[cur][0] + (size_t)row * 64 + ((lg * 16) ^ ((row & 3) << 4)));
    }
#pragma unroll
    for (int mi = 0; mi < 4; ++mi)
#pragma unroll
      for (int ni = 0; ni < 4; ++ni)
        acc[mi][ni] = __builtin_amdgcn_mfma_f32_16x16x32_bf16(a[mi], bb[ni], acc[mi][ni], 0, 0, 0);
    cur ^= 1;
  }
#pragma unroll
  for (int ni = 0; ni < 4; ++ni) {
    int col = n0 + wn * 64 + ni * 16 + lr;
    if (col >= Nvalid) continue;
    float bv = bias ? bias[col] : 0.f;
#pragma unroll
    for (int mi = 0; mi < 4; ++mi) {
      int rowb = m0 + wm * 64 + mi * 16 + lg * 4;
#pragma unroll
      for (int r = 0; r < 4; ++r)
        C[(size_t)(rowb + r) * ldC + col] = acc[mi][ni][r] + bv;
    }
  }
}

// Logits GEMM: 1D grid 2560, XCD-partitioned decode: xcd=id%8 owns n-tiles
// [xcd*10, xcd*10+10) so each XCD's 1.25MB B-slice stays L2-resident.
__global__ __launch_bounds__(256) void gemm_logits(
    const u16* __restrict__ A, const u16* __restrict__ B,
    float* __restrict__ C, const float* __restrict__ bias) {
  const int id = blockIdx.x;
  const int k8 = id & 7, j2 = id >> 3;
  const int n0 = (k8 * 10 + (j2 % 10)) * 128;
  const int m0 = (j2 / 10) * 128;
  const int tid = threadIdx.x, w = tid >> 6, l = tid & 63;
  const int wm = w >> 1, wn = w & 1;
  __shared__ __align__(16) u16 As[2][128 * 32];
  __shared__ __align__(16) u16 Bs[2][128 * 32];
  const f32x4 z4 = {0.f, 0.f, 0.f, 0.f};
  f32x4 acc[4][4];
#pragma unroll
  for (int a_ = 0; a_ < 4; ++a_)
#pragma unroll
    for (int b_ = 0; b_ < 4; ++b_) acc[a_][b_] = z4;

  const size_t rs = 1024;  // K=512 bf16

  auto stage = [&](int buf, int kt) {
    const char* Ab = (const char*)A + (size_t)m0 * rs + (size_t)kt * 64;
    const char* Bb = (const char*)B + (size_t)n0 * rs + (size_t)kt * 64;
#pragma unroll
    for (int j = 0; j < 2; ++j) {
      int c = j * 256 + tid;
      int row = c >> 2, off = ((c & 3) * 16) ^ ((row & 3) << 4);
      char* la = (char*)&As[buf][0] + (size_t)(j * 256 + w * 64) * 16;
      char* lb = (char*)&Bs[buf][0] + (size_t)(j * 256 + w * 64) * 16;
      gld16(Ab + (size_t)row * rs + off, la);
      gld16(Bb + (size_t)row * rs + off, lb);
    }
  };

  stage(0, 0);
  int cur = 0;
  const int lg = l >> 4, lr = l & 15;
  for (int kt = 0; kt < 16; ++kt) {
    __syncthreads();
    if (kt + 1 < 16) stage(cur ^ 1, kt + 1);
    short8 a[4], bb[4];
#pragma unroll
    for (int mi = 0; mi < 4; ++mi) {
      int row = wm * 64 + mi * 16 + lr;
      a[mi] = *(const short8*)((const char*)&As[cur][0] + (size_t)row * 64 + ((lg * 16) ^ ((row & 3) << 4)));
    }
#pragma unroll
    for (int ni = 0; ni < 4; ++ni) {
      int row = wn * 64 + ni * 16 + lr;
      bb[ni] = *(const short8*)((const char*)&Bs[cur][0] + (size_t)row * 64 + ((lg * 16) ^ ((row & 3) << 4)));
    }
#pragma unroll
    for (int mi = 0; mi < 4; ++mi)
#pragma unroll
      for (int ni = 0; ni < 4; ++ni)
        acc[mi][ni] = __builtin_amdgcn_mfma_f32_16x16x32_bf16(a[mi], bb[ni], acc[mi][ni], 0, 0, 0);
    cur ^= 1;
  }
#pragma unroll
  for (int ni = 0; ni < 4; ++ni) {
    int col = n0 + wn * 64 + ni * 16 + lr;
    if (col >= 10000) continue;
    float bv = bias[col];
#pragma unroll
    for (int mi = 0; mi < 4; ++mi) {
      int rowb = m0 + wm * 64 + mi * 16 + lg * 4;
#pragma unroll
      for (int r = 0; r < 4; ++r)
        C[(size_t)(rowb + r) * 10000 + col] = acc[mi][ni][r] + bv;
    }
  }
}

// ---------------------------------------------------------------------------
// Persistent cooperative decode loop. Grid = 128 blocks x 512 threads.
// Per step t: phase A (block b: reduce 8 gate partials + emb_pre -> LSTM
// pointwise -> h; then ph, scores, softmax, ctx) | gridbar | phase B
// (block (ns,ks): gates partial MFMA, 128b x 128 gate-rows x K=320) | gridbar.
// c-state persists in LDS for the whole kernel.
// ---------------------------------------------------------------------------
struct LoopArgs {
  float* gates_part;       // [8][128][2048]
  const float* emb_pre;    // [32][128][2048] (bias folded)
  u16* h_all;              // [128][32][512] bf16
  const u16* WahT8;        // [64][512][8] bf16
  const float* w_score;    // [512]
  const float* proj_feat;  // [128][49][512]
  const u16* feat_bf;      // [128][49][2048] bf16
  u16* ctx_bf;             // [128][2048] bf16
  const u16* Wcat;         // [2048 perm rows][2560] bf16
  const u16* zeros_bf;     // [512] bf16
  float* out_h;            // [128][512]
  float* out_c;            // [128][512]
  u32* bar;                // [2]
};

__global__ __launch_bounds__(512, 1) void decode_loop(LoopArgs A) {
  const int blk = blockIdx.x, tid = threadIdx.x;
  const int b = blk;
  const int ns = blk >> 3, ks = blk & 7;       // phase-B role
  const int w = tid >> 6, l = tid & 63;
  const int lg = l >> 4, lr = l & 15;
  const int wm = w >> 2, wn = w & 3;
  __shared__ float c_s[512], h_s[512], ph_s[512], ws_s[512];
  __shared__ float al_s[64];
  __shared__ __align__(16) u16 Xs[2][128 * 64];
  __shared__ __align__(16) u16 Ws[2][128 * 64];
  c_s[tid] = 0.f;
  ws_s[tid] = A.w_score[tid];

  for (int t = 0; t <= 32; ++t) {
    // ================= phase A (batch b) =================
    float hval = 0.f;
    if (t > 0) {
      const int j = tid;
      const size_t ss = (size_t)128 * 2048;
      const float* gp = A.gates_part + (size_t)b * 2048 + 4 * j;
      float4 s = *(const float4*)(A.emb_pre + ((size_t)(t - 1) * 128 + b) * 2048 + 4 * j);
#pragma unroll
      for (int p = 0; p < 8; ++p) {
        float4 g = *(const float4*)(gp + p * ss);
        s.x += g.x; s.y += g.y; s.z += g.z; s.w += g.w;
      }
      float c_old = c_s[j];
      float cn = sigm(s.y) * c_old + sigm(s.x) * fast_tanh(s.z);
      hval = sigm(s.w) * fast_tanh(cn);
      c_s[j] = cn;
      A.h_all[((size_t)b * 32 + (t - 1)) * 512 + j] = f2bf(hval);
      if (t == 32) { A.out_h[b * 512 + j] = hval; A.out_c[b * 512 + j] = cn; }
    }
    h_s[tid] = hval;
    __syncthreads();
    if (t == 32) break;

    float ph = 0.f;
    if (t > 0) {
#pragma unroll 4
      for (int kb = 0; kb < 64; ++kb) {
        u16x8 wv = *(const u16x8*)(A.WahT8 + (size_t)kb * 4096 + tid * 8);
#pragma unroll
        for (int e = 0; e < 8; ++e) ph = fmaf(bf2f(wv[e]), h_s[kb * 8 + e], ph);
      }
    }
    ph_s[tid] = ph;
    __syncthreads();

    for (int n = w; n < 49; n += 8) {
      const float* pf = A.proj_feat + ((size_t)b * 49 + n) * 512 + l * 8;
      float4 p0 = *(const float4*)pf;
      float4 p1 = *(const float4*)(pf + 4);
      const int k0 = l * 8;
      float s;
      s  = fast_tanh(p0.x + ph_s[k0 + 0]) * ws_s[k0 + 0];
      s += fast_tanh(p0.y + ph_s[k0 + 1]) * ws_s[k0 + 1];
      s += fast_tanh(p0.z + ph_s[k0 + 2]) * ws_s[k0 + 2];
      s += fast_tanh(p0.w + ph_s[k0 + 3]) * ws_s[k0 + 3];
      s += fast_tanh(p1.x + ph_s[k0 + 4]) * ws_s[k0 + 4];
      s += fast_tanh(p1.y + ph_s[k0 + 5]) * ws_s[k0 + 5];
      s += fast_tanh(p1.z + ph_s[k0 + 6]) * ws_s[k0 + 6];
      s += fast_tanh(p1.w + ph_s[k0 + 7]) * ws_s[k0 + 7];
#pragma unroll
      for (int off = 32; off > 0; off >>= 1) s += __shfl_down(s, off);
      if (l == 0) al_s[n] = s;
    }
    __syncthreads();
    if (tid < 64) {
      float v = (tid < 49) ? al_s[tid] : -1e30f;
      float m = v;
#pragma unroll
      for (int off = 32; off > 0; off >>= 1) m = fmaxf(m, __shfl_xor(m, off));
      float e = (tid < 49) ? __expf(v - m) : 0.f;
      float sm = e;
#pragma unroll
      for (int off = 32; off > 0; off >>= 1) sm += __shfl_xor(sm, off);
      if (tid < 49) al_s[tid] = e / sm;
    }
    __syncthreads();

    {
      float c0 = 0, c1 = 0, c2 = 0, c3 = 0;
      const u16* fb = A.feat_bf + (size_t)b * 49 * 2048 + tid * 4;
      for (int n = 0; n < 49; ++n) {
        float a = al_s[n];
        u16x4 v = *(const u16x4*)(fb + (size_t)n * 2048);
        c0 = fmaf(bf2f(v[0]), a, c0);
        c1 = fmaf(bf2f(v[1]), a, c1);
        c2 = fmaf(bf2f(v[2]), a, c2);
        c3 = fmaf(bf2f(v[3]), a, c3);
      }
      u16x4 o;
      o[0] = f2bf(c0); o[1] = f2bf(c1); o[2] = f2bf(c2); o[3] = f2bf(c3);
      *(u16x4*)(A.ctx_bf + (size_t)b * 2048 + tid * 4) = o;
    }

    gridbar(A.bar, 128);

    // ================= phase B (tile ns, k-split ks) =================
    const f32x4 z4 = {0.f, 0.f, 0.f, 0.f};
    f32x4 acc[4][2];
#pragma unroll
    for (int mi = 0; mi < 4; ++mi) { acc[mi][0] = z4; acc[mi][1] = z4; }

    auto stageB = [&](int buf, int kt) {
      const int kbase = ks * 640 + kt * 128;
#pragma unroll
      for (int it = 0; it < 2; ++it) {
        int c = it * 512 + tid;
        int row = c >> 3;
        int colb = kbase + (((c & 7) * 16) ^ ((row & 7) << 4));
        const char* g;
        if (colb < 4096)
          g = (const char*)A.ctx_bf + (size_t)row * 4096 + colb;
        else if (t > 0)
          g = (const char*)A.h_all + ((size_t)row * 32 + (t - 1)) * 1024 + (colb - 4096);
        else
          g = (const char*)A.zeros_bf + (colb - 4096);
        gld16(g, (char*)&Xs[buf][0] + (size_t)(it * 512 + w * 64) * 16);
        const char* gw = (const char*)A.Wcat + (size_t)(ns * 128 + row) * 5120 + colb;
        gld16(gw, (char*)&Ws[buf][0] + (size_t)(it * 512 + w * 64) * 16);
      }
    };

    stageB(0, 0);
    int cur = 0;
    for (int kt = 0; kt < 5; ++kt) {
      __syncthreads();
      if (kt + 1 < 5) stageB(cur ^ 1, kt + 1);
#pragma unroll
      for (int k2 = 0; k2 < 2; ++k2) {
        short8 av[4], bv[2];
#pragma unroll
        for (int mi = 0; mi < 4; ++mi) {
          int row = wm * 64 + mi * 16 + lr;
          av[mi] = *(const short8*)((const char*)&Xs[cur][0] + (size_t)row * 128 +
                                    ((k2 * 64 + lg * 16) ^ ((row & 7) << 4)));
        }
#pragma unroll
        for (int ni = 0; ni < 2; ++ni) {
          int row = wn * 32 + ni * 16 + lr;
          bv[ni] = *(const short8*)((const char*)&Ws[cur][0] + (size_t)row * 128 +
                                    ((k2 * 64 + lg * 16) ^ ((row & 7) << 4)));
        }
#pragma unroll
        for (int mi = 0; mi < 4; ++mi)
#pragma unroll
          for (int ni = 0; ni < 2; ++ni)
            acc[mi][ni] = __builtin_amdgcn_mfma_f32_16x16x32_bf16(av[mi], bv[ni], acc[mi][ni], 0, 0, 0);
      }
      cur ^= 1;
    }
    float* gp = A.gates_part + (size_t)ks * 128 * 2048;
#pragma unroll
    for (int mi = 0; mi < 4; ++mi)
#pragma unroll
      for (int ni = 0; ni < 2; ++ni) {
        int col = ns * 128 + wn * 32 + ni * 16 + lr;
#pragma unroll
        for (int r = 0; r < 4; ++r) {
          int m = wm * 64 + mi * 16 + lg * 4 + r;
          gp[(size_t)m * 2048 + col] = acc[mi][ni][r];
        }
      }

    gridbar(A.bar, 128);
  }
}

extern "C" void kernel_launch(void* const* d_in, const int* in_sizes, int n_in,
                              void* d_out, int out_size, void* d_ws, size_t ws_size,
                              hipStream_t stream) {
  (void)in_sizes; (void)n_in; (void)out_size; (void)ws_size;
  const float* features = (const float*)d_in[0];
  const int*   captions = (const int*)d_in[1];
  const float* embed_w  = (const float*)d_in[2];
  const float* Waf      = (const float*)d_in[3];
  const float* Wah      = (const float*)d_in[4];
  const float* w_score  = (const float*)d_in[5];
  const float* W_ih     = (const float*)d_in[6];
  const float* W_hh     = (const float*)d_in[7];
  const float* b_ih     = (const float*)d_in[8];
  const float* b_hh     = (const float*)d_in[9];
  const float* W_out    = (const float*)d_in[10];
  const float* b_out    = (const float*)d_in[11];

  // d_out scratch (all dead before the logits GEMM overwrites [0, 40.96M)):
  float* out = (float*)d_out;
  u16*   feat_bf   = (u16*)out;                    // 12,845,056 bf16
  float* proj_feat = out + 6422528;                // 3,211,264 f32
  float* emb_pre   = out + 9633792;                // 8,388,608 f32
  u16*   Wcat      = (u16*)(out + 18022400);       // 5,242,880 bf16
  u16*   Waf_bf    = (u16*)(out + 20643840);       // 1,048,576 bf16
  u16*   WahT8     = (u16*)(out + 21168128);       //   262,144 bf16
  u16*   Wemb      = (u16*)(out + 21299200);       // 1,048,576 bf16
  float* bias_perm = out + 21823488;               //     2,048 f32
  u16*   emb_bf    = (u16*)(out + 21825536);       // 2,097,152 bf16
  float* gates_part= out + 22874112;               // 2,097,152 f32 (8 splits)
  u16*   ctx_bf    = (u16*)(out + 24971264);       //   262,144 bf16
  float* out_h     = out + 40960000;
  float* out_c     = out_h + 65536;

  // ws: buffers live during the logits GEMM (+ barrier)
  char* wsp = (char*)d_ws;
  u16*   Wout_bf = (u16*)wsp;  wsp += 10485760;    // [10240][512] bf16
  u16*   h_all   = (u16*)wsp;  wsp += 4194304;     // [128][32][512] bf16
  u16*   zeros_bf= (u16*)wsp;  wsp += 1024;        // [512] bf16
  u32*   bar     = (u32*)wsp;  wsp += 8;           // [2]

  cast_all<<<8192, 256, 0, stream>>>(features, captions, embed_w, Waf, Wah,
      W_ih, W_hh, b_ih, b_hh, W_out, feat_bf, Waf_bf, WahT8, Wcat, Wemb,
      bias_perm, Wout_bf, emb_bf, zeros_bf, bar);

  // proj_feat [6272][512] = feat_bf [6272][2048] x Waf_bf [512][2048]^T
  gemm128<<<dim3(4, 49), 256, 0, stream>>>(feat_bf, Waf_bf, proj_feat,
                                           nullptr, 2048, 512, 512);
  // emb_pre [4096][2048] = emb_bf [4096][512] x Wemb [2048][512]^T + bias
  gemm128<<<dim3(16, 32), 256, 0, stream>>>(emb_bf, Wemb, emb_pre,
                                            bias_perm, 512, 2048, 2048);

  LoopArgs la;
  la.gates_part = gates_part; la.emb_pre = emb_pre; la.h_all = h_all;
  la.WahT8 = WahT8; la.w_score = w_score; la.proj_feat = proj_feat;
  la.feat_bf = feat_bf; la.ctx_bf = ctx_bf; la.Wcat = Wcat;
  la.zeros_bf = zeros_bf; la.out_h = out_h; la.out_c = out_c; la.bar = bar;
  void* kargs[] = { (void*)&la };
  hipLaunchCooperativeKernel((const void*)decode_loop, dim3(128), dim3(512),
                             kargs, 0, stream);

  // logits [4096][10000] = h_all [4096][512] x Wout_bf [10240][512]^T + b_out
  gemm_logits<<<2560, 256, 0, stream>>>(h_all, Wout_bf, out, b_out);
}

// Round 3
// 2467.423 us; speedup vs baseline: 1.1469x; 1.1469x over previous
//
#include <hip/hip_runtime.h>

typedef unsigned short u16;
typedef unsigned int u32;
typedef __attribute__((ext_vector_type(8))) short short8;
typedef __attribute__((ext_vector_type(8))) u16 u16x8;
typedef __attribute__((ext_vector_type(4))) u16 u16x4;
typedef __attribute__((ext_vector_type(4))) float f32x4;
typedef __attribute__((ext_vector_type(2))) u32 u32x2;

#define DEVINL static __device__ __forceinline__

DEVINL float bf2f(u16 u) { return __uint_as_float(((u32)u) << 16); }
DEVINL u16 f2bf(float f) {  // RNE round to bf16
  u32 x = __float_as_uint(f);
  u32 r = (x + 0x7fffu + ((x >> 16) & 1u)) >> 16;
  return (u16)r;
}
DEVINL float fast_tanh(float x) {
  float cx = fminf(fmaxf(x, -15.f), 15.f);
  float e = __expf(2.f * cx);
  return (e - 1.f) / (e + 1.f);
}
DEVINL float sigm(float x) { return 1.f / (1.f + __expf(-x)); }

typedef __attribute__((address_space(1))) const void gvoid;
typedef __attribute__((address_space(3))) void svoid;
DEVINL void gld16(const void* g, void* l) {
  __builtin_amdgcn_global_load_lds((gvoid*)g, (svoid*)l, 16, 0, 0);
}

// ---- cross-XCD coherent access helpers (sc0 sc1 = bypass L2 to coherence
// point; per LLVM gfx950 memory model these need NO cache maintenance) ----
DEVINL u32 ld_coh_u32(const u32* p) {
  u32 r;
  asm volatile("global_load_dword %0, %1, off sc0 sc1\n\ts_waitcnt vmcnt(0)"
               : "=v"(r) : "v"(p) : "memory");
  return r;
}
DEVINL void st_coh_f32(void* p, float v) {
  asm volatile("global_store_dword %0, %1, off sc0 sc1" :: "v"(p), "v"(v) : "memory");
}
DEVINL void st_coh_x2(void* p, u32x2 v) {
  asm volatile("global_store_dwordx2 %0, %1, off sc0 sc1" :: "v"(p), "v"(v) : "memory");
}
DEVINL void st_coh_short(void* p, u32 v) {
  asm volatile("global_store_short %0, %1, off sc0 sc1" :: "v"(p), "v"(v) : "memory");
}

// Grid barrier: monotonic count + generation; device-scope atomics (coherent,
// m20) + sc0sc1 spin load. NO fences -> read-only data stays L2-cached.
// Communicated data must itself use sc0sc1 accesses.
DEVINL void gridbar(u32* bar, u32 nblk, u32 target) {
  asm volatile("s_waitcnt vmcnt(0)" ::: "memory");
  __syncthreads();  // all waves drain vmcnt -> coherent stores visible
  if (threadIdx.x == 0) {
    if (atomicAdd(bar, 1u) % nblk == nblk - 1)
      atomicAdd(bar + 1, 1u);
    else
      while ((int)(ld_coh_u32(bar + 1) - target) < 0) __builtin_amdgcn_s_sleep(4);
  }
  __syncthreads();
}

// ---------------------------------------------------------------------------
// Phase 1: cast / gather / permute everything once (grid-stride, region table)
// perm row r <-> orig gate row o = (r&3)*512 + (r>>2)
// ---------------------------------------------------------------------------
__global__ __launch_bounds__(256) void cast_all(
    const float* __restrict__ features, const int* __restrict__ captions,
    const float* __restrict__ embed_w, const float* __restrict__ Waf,
    const float* __restrict__ Wah, const float* __restrict__ W_ih,
    const float* __restrict__ W_hh, const float* __restrict__ b_ih,
    const float* __restrict__ b_hh, const float* __restrict__ W_out,
    u16* __restrict__ feat_bf, u16* __restrict__ Waf_bf,
    u16* __restrict__ WahT8, u16* __restrict__ Wcat, u16* __restrict__ Wemb,
    float* __restrict__ bias_perm, u16* __restrict__ Wout_bf,
    u16* __restrict__ emb_bf, u16* __restrict__ zeros_bf,
    u32* __restrict__ bar) {
  long long i = (long long)blockIdx.x * 256 + threadIdx.x;
  const long long total = 27789826LL;
  const long long stride = (long long)gridDim.x * 256;
  for (; i < total; i += stride) {
    long long r = i;
    if (r < 12845056LL) { feat_bf[r] = f2bf(features[r]); continue; }
    r -= 12845056LL;
    if (r < 1048576LL) { Waf_bf[r] = f2bf(Waf[r]); continue; }
    r -= 1048576LL;
    if (r < 262144LL) {
      long long kb = r >> 12, rem = r & 4095;
      long long row = rem >> 3, e = rem & 7;
      WahT8[r] = f2bf(Wah[row * 512 + (kb * 8 + e)]);
      continue;
    }
    r -= 262144LL;
    if (r < 5242880LL) {
      long long pr = r / 2560, k = r % 2560;
      long long o = (pr & 3) * 512 + (pr >> 2);
      float v = (k < 2048) ? W_ih[o * 2560 + 512 + k] : W_hh[o * 512 + (k - 2048)];
      Wcat[r] = f2bf(v);
      continue;
    }
    r -= 5242880LL;
    if (r < 1048576LL) {
      long long pr = r >> 9, k = r & 511;
      long long o = (pr & 3) * 512 + (pr >> 2);
      Wemb[r] = f2bf(W_ih[o * 2560 + k]);
      continue;
    }
    r -= 1048576LL;
    if (r < 2048LL) {
      long long o = (r & 3) * 512 + (r >> 2);
      bias_perm[r] = b_ih[o] + b_hh[o];
      continue;
    }
    r -= 2048LL;
    if (r < 5242880LL) {
      long long row = r >> 9, k = r & 511;
      Wout_bf[r] = (row < 10000) ? f2bf(W_out[row * 512 + k]) : (u16)0;
      continue;
    }
    r -= 5242880LL;
    if (r < 2097152LL) {
      long long m = r >> 9, k = r & 511;
      long long tt = m >> 7, b = m & 127;
      int tok = captions[b * 32 + tt];
      tok = tok < 0 ? 0 : (tok > 9999 ? 9999 : tok);
      emb_bf[r] = f2bf(embed_w[(long long)tok * 512 + k]);
      continue;
    }
    r -= 2097152LL;
    if (r < 512LL) { zeros_bf[r] = 0; continue; }
    r -= 512LL;
    bar[r] = 0u;
  }
}

// ---------------------------------------------------------------------------
// 128x128 bf16 MFMA GEMM (2D grid): C[m][n] = sum_k A[m][k]*B[n][k] (+bias).
// ---------------------------------------------------------------------------
__global__ __launch_bounds__(256) void gemm128(
    const u16* __restrict__ A, const u16* __restrict__ B,
    float* __restrict__ C, const float* __restrict__ bias,
    int K, int ldC, int Nvalid) {
  const int n0 = blockIdx.x * 128, m0 = blockIdx.y * 128;
  const int tid = threadIdx.x, w = tid >> 6, l = tid & 63;
  const int wm = w >> 1, wn = w & 1;
  __shared__ __align__(16) u16 As[2][128 * 32];
  __shared__ __align__(16) u16 Bs[2][128 * 32];
  const f32x4 z4 = {0.f, 0.f, 0.f, 0.f};
  f32x4 acc[4][4];
#pragma unroll
  for (int a_ = 0; a_ < 4; ++a_)
#pragma unroll
    for (int b_ = 0; b_ < 4; ++b_) acc[a_][b_] = z4;

  const int NT = K >> 5;
  const size_t rs = (size_t)K * 2;

  auto stage = [&](int buf, int kt) {
    const char* Ab = (const char*)A + (size_t)m0 * rs + (size_t)kt * 64;
    const char* Bb = (const char*)B + (size_t)n0 * rs + (size_t)kt * 64;
#pragma unroll
    for (int j = 0; j < 2; ++j) {
      int c = j * 256 + tid;
      int row = c >> 2, off = ((c & 3) * 16) ^ ((row & 3) << 4);
      char* la = (char*)&As[buf][0] + (size_t)(j * 256 + w * 64) * 16;
      char* lb = (char*)&Bs[buf][0] + (size_t)(j * 256 + w * 64) * 16;
      gld16(Ab + (size_t)row * rs + off, la);
      gld16(Bb + (size_t)row * rs + off, lb);
    }
  };

  stage(0, 0);
  int cur = 0;
  const int lg = l >> 4, lr = l & 15;
  for (int kt = 0; kt < NT; ++kt) {
    __syncthreads();
    if (kt + 1 < NT) stage(cur ^ 1, kt + 1);
    short8 a[4], bb[4];
#pragma unroll
    for (int mi = 0; mi < 4; ++mi) {
      int row = wm * 64 + mi * 16 + lr;
      a[mi] = *(const short8*)((const char*)&As[cur][0] + (size_t)row * 64 + ((lg * 16) ^ ((row & 3) << 4)));
    }
#pragma unroll
    for (int ni = 0; ni < 4; ++ni) {
      int row = wn * 64 + ni * 16 + lr;
      bb[ni] = *(const short8*)((const char*)&Bs[cur][0] + (size_t)row * 64 + ((lg * 16) ^ ((row & 3) << 4)));
    }
#pragma unroll
    for (int mi = 0; mi < 4; ++mi)
#pragma unroll
      for (int ni = 0; ni < 4; ++ni)
        acc[mi][ni] = __builtin_amdgcn_mfma_f32_16x16x32_bf16(a[mi], bb[ni], acc[mi][ni], 0, 0, 0);
    cur ^= 1;
  }
#pragma unroll
  for (int ni = 0; ni < 4; ++ni) {
    int col = n0 + wn * 64 + ni * 16 + lr;
    if (col >= Nvalid) continue;
    float bv = bias ? bias[col] : 0.f;
#pragma unroll
    for (int mi = 0; mi < 4; ++mi) {
      int rowb = m0 + wm * 64 + mi * 16 + lg * 4;
#pragma unroll
      for (int r = 0; r < 4; ++r)
        C[(size_t)(rowb + r) * ldC + col] = acc[mi][ni][r] + bv;
    }
  }
}

// Logits GEMM: 1D grid 2560, XCD-partitioned: xcd=id%8 owns 10 n-tiles.
__global__ __launch_bounds__(256) void gemm_logits(
    const u16* __restrict__ A, const u16* __restrict__ B,
    float* __restrict__ C, const float* __restrict__ bias) {
  const int id = blockIdx.x;
  const int k8 = id & 7, j2 = id >> 3;
  const int n0 = (k8 * 10 + (j2 % 10)) * 128;
  const int m0 = (j2 / 10) * 128;
  const int tid = threadIdx.x, w = tid >> 6, l = tid & 63;
  const int wm = w >> 1, wn = w & 1;
  __shared__ __align__(16) u16 As[2][128 * 32];
  __shared__ __align__(16) u16 Bs[2][128 * 32];
  const f32x4 z4 = {0.f, 0.f, 0.f, 0.f};
  f32x4 acc[4][4];
#pragma unroll
  for (int a_ = 0; a_ < 4; ++a_)
#pragma unroll
    for (int b_ = 0; b_ < 4; ++b_) acc[a_][b_] = z4;

  const size_t rs = 1024;  // K=512 bf16

  auto stage = [&](int buf, int kt) {
    const char* Ab = (const char*)A + (size_t)m0 * rs + (size_t)kt * 64;
    const char* Bb = (const char*)B + (size_t)n0 * rs + (size_t)kt * 64;
#pragma unroll
    for (int j = 0; j < 2; ++j) {
      int c = j * 256 + tid;
      int row = c >> 2, off = ((c & 3) * 16) ^ ((row & 3) << 4);
      char* la = (char*)&As[buf][0] + (size_t)(j * 256 + w * 64) * 16;
      char* lb = (char*)&Bs[buf][0] + (size_t)(j * 256 + w * 64) * 16;
      gld16(Ab + (size_t)row * rs + off, la);
      gld16(Bb + (size_t)row * rs + off, lb);
    }
  };

  stage(0, 0);
  int cur = 0;
  const int lg = l >> 4, lr = l & 15;
  for (int kt = 0; kt < 16; ++kt) {
    __syncthreads();
    if (kt + 1 < 16) stage(cur ^ 1, kt + 1);
    short8 a[4], bb[4];
#pragma unroll
    for (int mi = 0; mi < 4; ++mi) {
      int row = wm * 64 + mi * 16 + lr;
      a[mi] = *(const short8*)((const char*)&As[cur][0] + (size_t)row * 64 + ((lg * 16) ^ ((row & 3) << 4)));
    }
#pragma unroll
    for (int ni = 0; ni < 4; ++ni) {
      int row = wn * 64 + ni * 16 + lr;
      bb[ni] = *(const short8*)((const char*)&Bs[cur][0] + (size_t)row * 64 + ((lg * 16) ^ ((row & 3) << 4)));
    }
#pragma unroll
    for (int mi = 0; mi < 4; ++mi)
#pragma unroll
      for (int ni = 0; ni < 4; ++ni)
        acc[mi][ni] = __builtin_amdgcn_mfma_f32_16x16x32_bf16(a[mi], bb[ni], acc[mi][ni], 0, 0, 0);
    cur ^= 1;
  }
#pragma unroll
  for (int ni = 0; ni < 4; ++ni) {
    int col = n0 + wn * 64 + ni * 16 + lr;
    if (col >= 10000) continue;
    float bv = bias[col];
#pragma unroll
    for (int mi = 0; mi < 4; ++mi) {
      int rowb = m0 + wm * 64 + mi * 16 + lg * 4;
#pragma unroll
      for (int r = 0; r < 4; ++r)
        C[(size_t)(rowb + r) * 10000 + col] = acc[mi][ni][r] + bv;
    }
  }
}

// ---------------------------------------------------------------------------
// Persistent cooperative decode loop. Grid = 128 blocks x 512 threads.
// Communicated data (gates_part, ctx_bf, h_all rows) via sc0sc1; read-only
// data (Wcat, proj_feat, feat_bf, WahT8, emb_pre) via normal cached loads ->
// stays L2-resident on each persistent block's XCD across all 32 steps.
// ---------------------------------------------------------------------------
struct LoopArgs {
  float* gates_part;       // [8][128][2048] f32  (coherent)
  const float* emb_pre;    // [32][128][2048] (bias folded)
  u16* h_all;              // [128][32][512] bf16 (coherent writes in-loop)
  const u16* WahT8;        // [64][512][8] bf16
  const float* w_score;    // [512]
  const float* proj_feat;  // [128][49][512]
  const u16* feat_bf;      // [128][49][2048] bf16
  u16* ctx_bf;             // [128][2048] bf16   (coherent)
  const u16* Wcat;         // [2048 perm rows][2560] bf16
  const u16* zeros_bf;     // [512] bf16
  float* out_h;            // [128][512]
  float* out_c;            // [128][512]
  u32* bar;                // [2] {count, gen}
};

__global__ __launch_bounds__(512, 1) void decode_loop(LoopArgs A) {
  const int blk = blockIdx.x, tid = threadIdx.x;
  const int b = blk;
  const int ns = blk >> 3, ks = blk & 7;       // phase-B role
  const int w = tid >> 6, l = tid & 63;
  const int lg = l >> 4, lr = l & 15;
  const int wm = w >> 2, wn = w & 3;
  __shared__ float c_s[512], h_s[512], ph_s[512], ws_s[512];
  __shared__ float al_s[64];
  __shared__ __align__(16) char Xall[128 * 640];   // 80 KiB, swizzled
  __shared__ __align__(16) u16 Ws[2][128 * 64];    // 32 KiB dbuf
  c_s[tid] = 0.f;
  ws_s[tid] = A.w_score[tid];
  u32 bno = 0;

  // phase-B constant addressing (precomputed)
  int abase[4], aswz[4];
#pragma unroll
  for (int mi = 0; mi < 4; ++mi) {
    int row = wm * 64 + mi * 16 + lr;
    abase[mi] = row * 640;
    aswz[mi] = (row & 7) << 4;
  }
  int bbase[2], bswz[2];
#pragma unroll
  for (int ni = 0; ni < 2; ++ni) {
    int row = wn * 32 + ni * 16 + lr;
    bbase[ni] = row * 128;
    bswz[ni] = (row & 7) << 4;
  }

  for (int t = 0; t <= 32; ++t) {
    // ================= phase A (batch b) =================
    float hval = 0.f;
    if (t > 0) {
      const int j = tid;
      const size_t ss = (size_t)128 * 2048;
      const float* gp = A.gates_part + (size_t)b * 2048 + 4 * j;
      f32x4 g0, g1, g2, g3, g4, g5, g6, g7;
      asm volatile(
          "global_load_dwordx4 %0, %8, off sc0 sc1\n\t"
          "global_load_dwordx4 %1, %9, off sc0 sc1\n\t"
          "global_load_dwordx4 %2, %10, off sc0 sc1\n\t"
          "global_load_dwordx4 %3, %11, off sc0 sc1\n\t"
          "global_load_dwordx4 %4, %12, off sc0 sc1\n\t"
          "global_load_dwordx4 %5, %13, off sc0 sc1\n\t"
          "global_load_dwordx4 %6, %14, off sc0 sc1\n\t"
          "global_load_dwordx4 %7, %15, off sc0 sc1\n\t"
          "s_waitcnt vmcnt(0)"
          : "=&v"(g0), "=&v"(g1), "=&v"(g2), "=&v"(g3),
            "=&v"(g4), "=&v"(g5), "=&v"(g6), "=&v"(g7)
          : "v"(gp), "v"(gp + ss), "v"(gp + 2 * ss), "v"(gp + 3 * ss),
            "v"(gp + 4 * ss), "v"(gp + 5 * ss), "v"(gp + 6 * ss), "v"(gp + 7 * ss)
          : "memory");
      float4 ep = *(const float4*)(A.emb_pre + ((size_t)(t - 1) * 128 + b) * 2048 + 4 * j);
      float iv = ep.x + g0[0] + g1[0] + g2[0] + g3[0] + g4[0] + g5[0] + g6[0] + g7[0];
      float fv = ep.y + g0[1] + g1[1] + g2[1] + g3[1] + g4[1] + g5[1] + g6[1] + g7[1];
      float gv = ep.z + g0[2] + g1[2] + g2[2] + g3[2] + g4[2] + g5[2] + g6[2] + g7[2];
      float ov = ep.w + g0[3] + g1[3] + g2[3] + g3[3] + g4[3] + g5[3] + g6[3] + g7[3];
      float c_old = c_s[j];
      float cn = sigm(fv) * c_old + sigm(iv) * fast_tanh(gv);
      hval = sigm(ov) * fast_tanh(cn);
      c_s[j] = cn;
      st_coh_short(A.h_all + ((size_t)b * 32 + (t - 1)) * 512 + j, (u32)f2bf(hval));
      if (t == 32) { A.out_h[b * 512 + j] = hval; A.out_c[b * 512 + j] = cn; }
    }
    h_s[tid] = hval;
    __syncthreads();
    if (t == 32) break;

    float ph = 0.f;
    if (t > 0) {
#pragma unroll 4
      for (int kb = 0; kb < 64; ++kb) {
        u16x8 wv = *(const u16x8*)(A.WahT8 + (size_t)kb * 4096 + tid * 8);
#pragma unroll
        for (int e = 0; e < 8; ++e) ph = fmaf(bf2f(wv[e]), h_s[kb * 8 + e], ph);
      }
    }
    ph_s[tid] = ph;
    __syncthreads();

    for (int n = w; n < 49; n += 8) {
      const float* pf = A.proj_feat + ((size_t)b * 49 + n) * 512 + l * 8;
      float4 p0 = *(const float4*)pf;
      float4 p1 = *(const float4*)(pf + 4);
      const int k0 = l * 8;
      float s;
      s  = fast_tanh(p0.x + ph_s[k0 + 0]) * ws_s[k0 + 0];
      s += fast_tanh(p0.y + ph_s[k0 + 1]) * ws_s[k0 + 1];
      s += fast_tanh(p0.z + ph_s[k0 + 2]) * ws_s[k0 + 2];
      s += fast_tanh(p0.w + ph_s[k0 + 3]) * ws_s[k0 + 3];
      s += fast_tanh(p1.x + ph_s[k0 + 4]) * ws_s[k0 + 4];
      s += fast_tanh(p1.y + ph_s[k0 + 5]) * ws_s[k0 + 5];
      s += fast_tanh(p1.z + ph_s[k0 + 6]) * ws_s[k0 + 6];
      s += fast_tanh(p1.w + ph_s[k0 + 7]) * ws_s[k0 + 7];
#pragma unroll
      for (int off = 32; off > 0; off >>= 1) s += __shfl_down(s, off);
      if (l == 0) al_s[n] = s;
    }
    __syncthreads();
    if (tid < 64) {
      float v = (tid < 49) ? al_s[tid] : -1e30f;
      float m = v;
#pragma unroll
      for (int off = 32; off > 0; off >>= 1) m = fmaxf(m, __shfl_xor(m, off));
      float e = (tid < 49) ? __expf(v - m) : 0.f;
      float sm = e;
#pragma unroll
      for (int off = 32; off > 0; off >>= 1) sm += __shfl_xor(sm, off);
      if (tid < 49) al_s[tid] = e / sm;
    }
    __syncthreads();

    {
      float c0 = 0, c1 = 0, c2 = 0, c3 = 0;
      const u16* fb = A.feat_bf + (size_t)b * 49 * 2048 + tid * 4;
      for (int n = 0; n < 49; ++n) {
        float a = al_s[n];
        u16x4 v = *(const u16x4*)(fb + (size_t)n * 2048);
        c0 = fmaf(bf2f(v[0]), a, c0);
        c1 = fmaf(bf2f(v[1]), a, c1);
        c2 = fmaf(bf2f(v[2]), a, c2);
        c3 = fmaf(bf2f(v[3]), a, c3);
      }
      u32x2 o2;
      o2[0] = (u32)f2bf(c0) | ((u32)f2bf(c1) << 16);
      o2[1] = (u32)f2bf(c2) | ((u32)f2bf(c3) << 16);
      st_coh_x2(A.ctx_bf + (size_t)b * 2048 + tid * 4, o2);
    }

    gridbar(A.bar, 128, ++bno);

    // ================= phase B (tile ns, k-split ks) =================
    // Stage the whole X K-slice ([128 rows][320 bf16] of [ctx|h]) coherent ->
    // LDS (swizzled). 5120 16B-units / 512 thr = 10 per thread.
#pragma unroll
    for (int half = 0; half < 2; ++half) {
      const char *s0, *s1, *s2, *s3, *s4;
      int o0, o1, o2_, o3, o4;
#define XCHUNK(i, S, O)                                                       \
  {                                                                           \
    int c = (half * 5 + (i)) * 512 + tid;                                     \
    int row = c / 40, u = c % 40;                                             \
    int gcol = ks * 640 + u * 16;                                             \
    if (gcol < 4096) S = (const char*)A.ctx_bf + (size_t)row * 4096 + gcol;   \
    else if (t > 0)                                                           \
      S = (const char*)A.h_all + ((size_t)row * 32 + (t - 1)) * 1024 + (gcol - 4096); \
    else S = (const char*)A.zeros_bf + (gcol - 4096);                         \
    O = row * 640 + ((u * 16) ^ ((row & 7) << 4));                            \
  }
      XCHUNK(0, s0, o0) XCHUNK(1, s1, o1) XCHUNK(2, s2, o2_)
      XCHUNK(3, s3, o3) XCHUNK(4, s4, o4)
#undef XCHUNK
      f32x4 d0, d1, d2, d3, d4;
      asm volatile(
          "global_load_dwordx4 %0, %5, off sc0 sc1\n\t"
          "global_load_dwordx4 %1, %6, off sc0 sc1\n\t"
          "global_load_dwordx4 %2, %7, off sc0 sc1\n\t"
          "global_load_dwordx4 %3, %8, off sc0 sc1\n\t"
          "global_load_dwordx4 %4, %9, off sc0 sc1\n\t"
          "s_waitcnt vmcnt(0)"
          : "=&v"(d0), "=&v"(d1), "=&v"(d2), "=&v"(d3), "=&v"(d4)
          : "v"(s0), "v"(s1), "v"(s2), "v"(s3), "v"(s4)
          : "memory");
      *(f32x4*)(Xall + o0) = d0;
      *(f32x4*)(Xall + o1) = d1;
      *(f32x4*)(Xall + o2_) = d2;
      *(f32x4*)(Xall + o3) = d3;
      *(f32x4*)(Xall + o4) = d4;
    }

    const f32x4 z4 = {0.f, 0.f, 0.f, 0.f};
    f32x4 acc[4][2];
#pragma unroll
    for (int mi = 0; mi < 4; ++mi) { acc[mi][0] = z4; acc[mi][1] = z4; }

    auto stageW = [&](int buf, int kt) {
      const int kbase = ks * 640 + kt * 128;
#pragma unroll
      for (int j = 0; j < 2; ++j) {
        int c = j * 512 + tid;
        int row = c >> 3;
        int colb = kbase + (((c & 7) * 16) ^ ((row & 7) << 4));
        const char* gw = (const char*)A.Wcat + (size_t)(ns * 128 + row) * 5120 + colb;
        gld16(gw, (char*)&Ws[buf][0] + (size_t)(j * 512 + w * 64) * 16);
      }
    };

    stageW(0, 0);
    __syncthreads();  // Xall ready (also orders first stageW issue)
    int cur = 0;
    for (int kt = 0; kt < 5; ++kt) {
      __syncthreads();
      if (kt + 1 < 5) stageW(cur ^ 1, kt + 1);
#pragma unroll
      for (int k2 = 0; k2 < 2; ++k2) {
        short8 av[4], bv[2];
#pragma unroll
        for (int mi = 0; mi < 4; ++mi)
          av[mi] = *(const short8*)(Xall + abase[mi] +
                                    ((kt * 128 + k2 * 64 + lg * 16) ^ aswz[mi]));
#pragma unroll
        for (int ni = 0; ni < 2; ++ni)
          bv[ni] = *(const short8*)((const char*)&Ws[cur][0] + bbase[ni] +
                                    ((k2 * 64 + lg * 16) ^ bswz[ni]));
#pragma unroll
        for (int mi = 0; mi < 4; ++mi)
#pragma unroll
          for (int ni = 0; ni < 2; ++ni)
            acc[mi][ni] = __builtin_amdgcn_mfma_f32_16x16x32_bf16(av[mi], bv[ni], acc[mi][ni], 0, 0, 0);
      }
      cur ^= 1;
    }
    float* gp = A.gates_part + (size_t)ks * 128 * 2048;
#pragma unroll
    for (int mi = 0; mi < 4; ++mi)
#pragma unroll
      for (int ni = 0; ni < 2; ++ni) {
        int col = ns * 128 + wn * 32 + ni * 16 + lr;
#pragma unroll
        for (int r = 0; r < 4; ++r) {
          int m = wm * 64 + mi * 16 + lg * 4 + r;
          st_coh_f32(&gp[(size_t)m * 2048 + col], acc[mi][ni][r]);
        }
      }

    gridbar(A.bar, 128, ++bno);
  }
}

extern "C" void kernel_launch(void* const* d_in, const int* in_sizes, int n_in,
                              void* d_out, int out_size, void* d_ws, size_t ws_size,
                              hipStream_t stream) {
  (void)in_sizes; (void)n_in; (void)out_size; (void)ws_size;
  const float* features = (const float*)d_in[0];
  const int*   captions = (const int*)d_in[1];
  const float* embed_w  = (const float*)d_in[2];
  const float* Waf      = (const float*)d_in[3];
  const float* Wah      = (const float*)d_in[4];
  const float* w_score  = (const float*)d_in[5];
  const float* W_ih     = (const float*)d_in[6];
  const float* W_hh     = (const float*)d_in[7];
  const float* b_ih     = (const float*)d_in[8];
  const float* b_hh     = (const float*)d_in[9];
  const float* W_out    = (const float*)d_in[10];
  const float* b_out    = (const float*)d_in[11];

  // d_out scratch (all dead before the logits GEMM overwrites [0, 40.96M)):
  float* out = (float*)d_out;
  u16*   feat_bf   = (u16*)out;                    // 12,845,056 bf16
  float* proj_feat = out + 6422528;                // 3,211,264 f32
  float* emb_pre   = out + 9633792;                // 8,388,608 f32
  u16*   Wcat      = (u16*)(out + 18022400);       // 5,242,880 bf16
  u16*   Waf_bf    = (u16*)(out + 20643840);       // 1,048,576 bf16
  u16*   WahT8     = (u16*)(out + 21168128);       //   262,144 bf16
  u16*   Wemb      = (u16*)(out + 21299200);       // 1,048,576 bf16
  float* bias_perm = out + 21823488;               //     2,048 f32
  u16*   emb_bf    = (u16*)(out + 21825536);       // 2,097,152 bf16
  float* gates_part= out + 22874112;               // 2,097,152 f32 (8 splits)
  u16*   ctx_bf    = (u16*)(out + 24971264);       //   262,144 bf16
  float* out_h     = out + 40960000;
  float* out_c     = out_h + 65536;

  // ws: buffers live during the logits GEMM (+ barrier)
  char* wsp = (char*)d_ws;
  u16*   Wout_bf = (u16*)wsp;  wsp += 10485760;    // [10240][512] bf16
  u16*   h_all   = (u16*)wsp;  wsp += 4194304;     // [128][32][512] bf16
  u16*   zeros_bf= (u16*)wsp;  wsp += 1024;        // [512] bf16
  u32*   bar     = (u32*)wsp;  wsp += 8;           // [2]

  cast_all<<<8192, 256, 0, stream>>>(features, captions, embed_w, Waf, Wah,
      W_ih, W_hh, b_ih, b_hh, W_out, feat_bf, Waf_bf, WahT8, Wcat, Wemb,
      bias_perm, Wout_bf, emb_bf, zeros_bf, bar);

  // proj_feat [6272][512] = feat_bf [6272][2048] x Waf_bf [512][2048]^T
  gemm128<<<dim3(4, 49), 256, 0, stream>>>(feat_bf, Waf_bf, proj_feat,
                                           nullptr, 2048, 512, 512);
  // emb_pre [4096][2048] = emb_bf [4096][512] x Wemb [2048][512]^T + bias
  gemm128<<<dim3(16, 32), 256, 0, stream>>>(emb_bf, Wemb, emb_pre,
                                            bias_perm, 512, 2048, 2048);

  LoopArgs la;
  la.gates_part = gates_part; la.emb_pre = emb_pre; la.h_all = h_all;
  la.WahT8 = WahT8; la.w_score = w_score; la.proj_feat = proj_feat;
  la.feat_bf = feat_bf; la.ctx_bf = ctx_bf; la.Wcat = Wcat;
  la.zeros_bf = zeros_bf; la.out_h = out_h; la.out_c = out_c; la.bar = bar;
  void* kargs[] = { (void*)&la };
  hipLaunchCooperativeKernel((const void*)decode_loop, dim3(128), dim3(512),
                             kargs, 0, stream);

  // logits [4096][10000] = h_all [4096][512] x Wout_bf [10240][512]^T + b_out
  gemm_logits<<<2560, 256, 0, stream>>>(h_all, Wout_bf, out, b_out);
}